// Round 16
// baseline (145.596 us; speedup 1.0000x reference)
//
#include <hip/hip_runtime.h>

#define BH  64
#define SEQ 4096
#define DH  64
#define NCHUNK 16
#define CROWS  (SEQ / NCHUNK)   // 256 s-rows per chunk

// ---------------------------------------------------------------------------
// Kernel 1: partial kv = k^T v over a 256-row chunk. One (b,h,chunk)/block.
// out_kernel-shaped: zero LDS, zero barriers, per-lane float4 ROW loads,
// tiny VGPR, high occupancy.
// 256 threads = 4 waves. Wave w owns output d-rows [w*16, w*16+16).
// Lane l: dg = l>>4 -> d0 = w*16 + dg*4; eg = l&15 -> e0 = eg*4.
// Per s: k4 = k[s][d0:4] (4 distinct 16B segs/wave, 16x dup -> merged),
//        v4 = v[s][e0:4] (16 distinct 16B segs/wave, 4x dup -> merged),
//        16 FMA into acc[4][4]. No cross-wave reduce: wave writes its own
//        16 rows of partial. Pure fp32 (absmax back to 8).
// Floors: FMA-issue 13.7 us, HBM 20 us -> HBM-bound target ~25 us.
// ---------------------------------------------------------------------------
__global__ __launch_bounds__(256) void kv_partial_kernel(
    const float* __restrict__ k, const float* __restrict__ v,
    float* __restrict__ partial) {
  const int t = threadIdx.x;
  const int bh = blockIdx.x >> 4;             // / NCHUNK
  const int chunk = blockIdx.x & (NCHUNK - 1);
  const int l  = t & 63;
  const int w  = t >> 6;
  const int dg = l >> 4;      // 0..3
  const int eg = l & 15;      // 0..15
  const int drow = w * 16 + dg * 4;   // this lane's 4 output d-rows
  const int e0 = eg * 4;              // this lane's 4 output e-cols

  const size_t base = (size_t)bh * SEQ * DH + (size_t)chunk * CROWS * DH;
  const float* kp = k + base + drow;
  const float* vp = v + base + e0;

  float acc[4][4];
#pragma unroll
  for (int i = 0; i < 4; ++i)
#pragma unroll
    for (int j = 0; j < 4; ++j) acc[i][j] = 0.f;

#pragma unroll 4
  for (int s = 0; s < CROWS; ++s) {
    float4 k4 = *(const float4*)(kp + (size_t)s * DH);
    float4 v4 = *(const float4*)(vp + (size_t)s * DH);
    float kk[4] = {k4.x, k4.y, k4.z, k4.w};
    float vv[4] = {v4.x, v4.y, v4.z, v4.w};
#pragma unroll
    for (int i = 0; i < 4; ++i)
#pragma unroll
      for (int j = 0; j < 4; ++j) acc[i][j] += kk[i] * vv[j];
  }

  float* pb = partial + (size_t)blockIdx.x * (DH * DH);
#pragma unroll
  for (int i = 0; i < 4; ++i) {
    float4 x = {acc[i][0], acc[i][1], acc[i][2], acc[i][3]};
    *(float4*)&pb[(size_t)(drow + i) * 64 + e0] = x;
  }
}

// ---------------------------------------------------------------------------
// Kernel 2: reduce partials -> kvf [BH][64*64]. 256 blocks x 256 threads
// covers 65536 float4 slots.
// ---------------------------------------------------------------------------
__global__ __launch_bounds__(256) void kv_reduce_kernel(
    const float* __restrict__ partial, float* __restrict__ kvf) {
  const int gid = blockIdx.x * 256 + threadIdx.x;
  const int bh = gid >> 10;
  const int idx = gid & 1023;
  float4 s = {0.f, 0.f, 0.f, 0.f};
  for (int c = 0; c < NCHUNK; ++c) {
    const float4* p = (const float4*)(partial + ((size_t)bh * NCHUNK + c) * (DH * DH));
    float4 x = p[idx];
    s.x += x.x; s.y += x.y; s.z += x.z; s.w += x.w;
  }
  ((float4*)kvf)[gid] = s;
}

// ---------------------------------------------------------------------------
// Kernel 3: out = q @ kv. Block = 64 q-rows. Thread = 1 row x 16 cols.
// Entire q row hoisted to registers up front; kv in LDS, broadcast reads.
// Near its BW roofline (~19 us, 6.7 TB/s effective) -- unchanged.
// ---------------------------------------------------------------------------
__global__ __launch_bounds__(256) void out_kernel(
    const float* __restrict__ q, const float* __restrict__ kvf,
    float* __restrict__ out) {
  const int t = threadIdx.x;
  const int bh = blockIdx.x >> 6;
  const int rb = blockIdx.x & 63;
  const int row = rb * 64 + (t >> 2);
  const int c0 = (t & 3) * 16;

  __shared__ float kv_lds[64 * 64];

  const float4* gkv4 = (const float4*)(kvf + (size_t)bh * (DH * DH));
  float4* kv4 = (float4*)kv_lds;
#pragma unroll
  for (int j = 0; j < 4; ++j) kv4[t + j * 256] = gkv4[t + j * 256];

  const float* qrow = q + (size_t)bh * SEQ * DH + (size_t)row * DH;
  float4 qv[16];
#pragma unroll
  for (int i = 0; i < 16; ++i) qv[i] = *(const float4*)&qrow[i * 4];

  __syncthreads();

  float acc[16];
#pragma unroll
  for (int j = 0; j < 16; ++j) acc[j] = 0.f;

#pragma unroll
  for (int dc = 0; dc < 16; ++dc) {
    float qs[4] = {qv[dc].x, qv[dc].y, qv[dc].z, qv[dc].w};
#pragma unroll
    for (int dd = 0; dd < 4; ++dd) {
      const float* kr = &kv_lds[(dc * 4 + dd) * 64 + c0];
      float4 k0 = *(const float4*)&kr[0];
      float4 k1 = *(const float4*)&kr[4];
      float4 k2 = *(const float4*)&kr[8];
      float4 k3 = *(const float4*)&kr[12];
      const float qsv = qs[dd];
      acc[0]  += qsv * k0.x; acc[1]  += qsv * k0.y;
      acc[2]  += qsv * k0.z; acc[3]  += qsv * k0.w;
      acc[4]  += qsv * k1.x; acc[5]  += qsv * k1.y;
      acc[6]  += qsv * k1.z; acc[7]  += qsv * k1.w;
      acc[8]  += qsv * k2.x; acc[9]  += qsv * k2.y;
      acc[10] += qsv * k2.z; acc[11] += qsv * k2.w;
      acc[12] += qsv * k3.x; acc[13] += qsv * k3.y;
      acc[14] += qsv * k3.z; acc[15] += qsv * k3.w;
    }
  }

  float* ob = out + (size_t)bh * SEQ * DH + (size_t)row * DH + c0;
#pragma unroll
  for (int j = 0; j < 4; ++j) {
    float4 w = {acc[4 * j + 0], acc[4 * j + 1], acc[4 * j + 2], acc[4 * j + 3]};
    *(float4*)&ob[4 * j] = w;
  }
}

// ---------------------------------------------------------------------------
extern "C" void kernel_launch(void* const* d_in, const int* in_sizes, int n_in,
                              void* d_out, int out_size, void* d_ws, size_t ws_size,
                              hipStream_t stream) {
  const float* q = (const float*)d_in[0];
  const float* k = (const float*)d_in[1];
  const float* v = (const float*)d_in[2];
  float* out = (float*)d_out;

  float* kvf = (float*)d_ws;                      // [BH][64*64] = 1 MB
  float* partial = kvf + (size_t)BH * DH * DH;    // [BH*NCHUNK][64*64] = 16 MB

  hipLaunchKernelGGL(kv_partial_kernel, dim3(BH * NCHUNK), dim3(256), 0, stream,
                     k, v, partial);
  hipLaunchKernelGGL(kv_reduce_kernel, dim3(256), dim3(256), 0, stream,
                     partial, kvf);
  hipLaunchKernelGGL(out_kernel, dim3(BH * 64), dim3(256), 0, stream,
                     q, kvf, out);
}

// Round 18
// 129.019 us; speedup vs baseline: 1.1285x; 1.1285x over previous
//
#include <hip/hip_runtime.h>

#define BH  64
#define SEQ 4096
#define DH  64
#define NCHUNK 16
#define CROWS  (SEQ / NCHUNK)   // 256 s-rows per chunk

// ---------------------------------------------------------------------------
// Kernel 1: partial kv = k^T v over a 256-row chunk. One (b,h,chunk)/block.
// 256 threads = 4 waves; wave w owns output d-rows [w*16, w*16+16); lane:
// dg=l>>4 -> d0=w*16+dg*4 (4 k-cols), eg=l&15 -> e0=eg*4 (4 v-cols).
// Inline-asm batch of 16 global_load_dwordx4 (8 k-rows + 8 v-rows via 64-bit
// per-lane address pairs + offset:0..1792) ending in s_waitcnt vmcnt(0)
// INSIDE the blob. "=&v" EARLY-CLOBBER outputs (round-17 fault: "=v" let
// load 1 overwrite the address regs of loads 2-16). 16 loads in flight per
// wave guaranteed; ~90 VGPR live; launch_bounds(256,4) grants 128.
// Zero LDS, zero barriers; wave writes its own 16 partial rows. Pure fp32.
// ---------------------------------------------------------------------------
__global__ __launch_bounds__(256, 4) void kv_partial_kernel(
    const float* __restrict__ k, const float* __restrict__ v,
    float* __restrict__ partial) {
  const int t = threadIdx.x;
  const int bh = blockIdx.x >> 4;             // / NCHUNK
  const int chunk = blockIdx.x & (NCHUNK - 1);
  const int l  = t & 63;
  const int w  = t >> 6;
  const int dg = l >> 4;      // 0..3
  const int eg = l & 15;      // 0..15
  const int drow = w * 16 + dg * 4;   // this lane's 4 output d-rows (k cols)
  const int e0 = eg * 4;              // this lane's 4 output e-cols (v cols)

  const size_t base = (size_t)bh * SEQ * DH + (size_t)chunk * CROWS * DH;
  const float* kp = k + base + drow;   // per-lane: k[s][drow..drow+4)
  const float* vp = v + base + e0;     // per-lane: v[s][e0..e0+4)

  float acc[4][4];
#pragma unroll
  for (int i = 0; i < 4; ++i)
#pragma unroll
    for (int j = 0; j < 4; ++j) acc[i][j] = 0.f;

#pragma unroll 1
  for (int b = 0; b < CROWS / 8; ++b) {
    const float* kb8 = kp + (size_t)b * 8 * DH;   // 8 rows, 256 B stride
    const float* vb8 = vp + (size_t)b * 8 * DH;
    float4 ka[8], va[8];
    asm volatile(
        "global_load_dwordx4 %0, %16, off\n\t"
        "global_load_dwordx4 %1, %16, off offset:256\n\t"
        "global_load_dwordx4 %2, %16, off offset:512\n\t"
        "global_load_dwordx4 %3, %16, off offset:768\n\t"
        "global_load_dwordx4 %4, %16, off offset:1024\n\t"
        "global_load_dwordx4 %5, %16, off offset:1280\n\t"
        "global_load_dwordx4 %6, %16, off offset:1536\n\t"
        "global_load_dwordx4 %7, %16, off offset:1792\n\t"
        "global_load_dwordx4 %8, %17, off\n\t"
        "global_load_dwordx4 %9, %17, off offset:256\n\t"
        "global_load_dwordx4 %10, %17, off offset:512\n\t"
        "global_load_dwordx4 %11, %17, off offset:768\n\t"
        "global_load_dwordx4 %12, %17, off offset:1024\n\t"
        "global_load_dwordx4 %13, %17, off offset:1280\n\t"
        "global_load_dwordx4 %14, %17, off offset:1536\n\t"
        "global_load_dwordx4 %15, %17, off offset:1792\n\t"
        "s_waitcnt vmcnt(0)"
        : "=&v"(ka[0]), "=&v"(ka[1]), "=&v"(ka[2]), "=&v"(ka[3]),
          "=&v"(ka[4]), "=&v"(ka[5]), "=&v"(ka[6]), "=&v"(ka[7]),
          "=&v"(va[0]), "=&v"(va[1]), "=&v"(va[2]), "=&v"(va[3]),
          "=&v"(va[4]), "=&v"(va[5]), "=&v"(va[6]), "=&v"(va[7])
        : "v"(kb8), "v"(vb8)
        : "memory");

#pragma unroll
    for (int r = 0; r < 8; ++r) {
      float kk[4] = {ka[r].x, ka[r].y, ka[r].z, ka[r].w};
      float vv[4] = {va[r].x, va[r].y, va[r].z, va[r].w};
#pragma unroll
      for (int i = 0; i < 4; ++i)
#pragma unroll
        for (int j = 0; j < 4; ++j) acc[i][j] += kk[i] * vv[j];
    }
  }

  float* pb = partial + (size_t)blockIdx.x * (DH * DH);
#pragma unroll
  for (int i = 0; i < 4; ++i) {
    float4 x = {acc[i][0], acc[i][1], acc[i][2], acc[i][3]};
    *(float4*)&pb[(size_t)(drow + i) * 64 + e0] = x;
  }
}

// ---------------------------------------------------------------------------
// Kernel 2: reduce partials -> kvf [BH][64*64]. 256 blocks x 256 threads
// covers 65536 float4 slots.
// ---------------------------------------------------------------------------
__global__ __launch_bounds__(256) void kv_reduce_kernel(
    const float* __restrict__ partial, float* __restrict__ kvf) {
  const int gid = blockIdx.x * 256 + threadIdx.x;
  const int bh = gid >> 10;
  const int idx = gid & 1023;
  float4 s = {0.f, 0.f, 0.f, 0.f};
  for (int c = 0; c < NCHUNK; ++c) {
    const float4* p = (const float4*)(partial + ((size_t)bh * NCHUNK + c) * (DH * DH));
    float4 x = p[idx];
    s.x += x.x; s.y += x.y; s.z += x.z; s.w += x.w;
  }
  ((float4*)kvf)[gid] = s;
}

// ---------------------------------------------------------------------------
// Kernel 3: out = q @ kv. Block = 64 q-rows. Thread = 1 row x 16 cols.
// Entire q row hoisted to registers up front; kv in LDS, broadcast reads.
// Near its BW roofline (~19 us, 6.7 TB/s effective) -- unchanged.
// ---------------------------------------------------------------------------
__global__ __launch_bounds__(256) void out_kernel(
    const float* __restrict__ q, const float* __restrict__ kvf,
    float* __restrict__ out) {
  const int t = threadIdx.x;
  const int bh = blockIdx.x >> 6;
  const int rb = blockIdx.x & 63;
  const int row = rb * 64 + (t >> 2);
  const int c0 = (t & 3) * 16;

  __shared__ float kv_lds[64 * 64];

  const float4* gkv4 = (const float4*)(kvf + (size_t)bh * (DH * DH));
  float4* kv4 = (float4*)kv_lds;
#pragma unroll
  for (int j = 0; j < 4; ++j) kv4[t + j * 256] = gkv4[t + j * 256];

  const float* qrow = q + (size_t)bh * SEQ * DH + (size_t)row * DH;
  float4 qv[16];
#pragma unroll
  for (int i = 0; i < 16; ++i) qv[i] = *(const float4*)&qrow[i * 4];

  __syncthreads();

  float acc[16];
#pragma unroll
  for (int j = 0; j < 16; ++j) acc[j] = 0.f;

#pragma unroll
  for (int dc = 0; dc < 16; ++dc) {
    float qs[4] = {qv[dc].x, qv[dc].y, qv[dc].z, qv[dc].w};
#pragma unroll
    for (int dd = 0; dd < 4; ++dd) {
      const float* kr = &kv_lds[(dc * 4 + dd) * 64 + c0];
      float4 k0 = *(const float4*)&kr[0];
      float4 k1 = *(const float4*)&kr[4];
      float4 k2 = *(const float4*)&kr[8];
      float4 k3 = *(const float4*)&kr[12];
      const float qsv = qs[dd];
      acc[0]  += qsv * k0.x; acc[1]  += qsv * k0.y;
      acc[2]  += qsv * k0.z; acc[3]  += qsv * k0.w;
      acc[4]  += qsv * k1.x; acc[5]  += qsv * k1.y;
      acc[6]  += qsv * k1.z; acc[7]  += qsv * k1.w;
      acc[8]  += qsv * k2.x; acc[9]  += qsv * k2.y;
      acc[10] += qsv * k2.z; acc[11] += qsv * k2.w;
      acc[12] += qsv * k3.x; acc[13] += qsv * k3.y;
      acc[14] += qsv * k3.z; acc[15] += qsv * k3.w;
    }
  }

  float* ob = out + (size_t)bh * SEQ * DH + (size_t)row * DH + c0;
#pragma unroll
  for (int j = 0; j < 4; ++j) {
    float4 w = {acc[4 * j + 0], acc[4 * j + 1], acc[4 * j + 2], acc[4 * j + 3]};
    *(float4*)&ob[4 * j] = w;
  }
}

// ---------------------------------------------------------------------------
extern "C" void kernel_launch(void* const* d_in, const int* in_sizes, int n_in,
                              void* d_out, int out_size, void* d_ws, size_t ws_size,
                              hipStream_t stream) {
  const float* q = (const float*)d_in[0];
  const float* k = (const float*)d_in[1];
  const float* v = (const float*)d_in[2];
  float* out = (float*)d_out;

  float* kvf = (float*)d_ws;                      // [BH][64*64] = 1 MB
  float* partial = kvf + (size_t)BH * DH * DH;    // [BH*NCHUNK][64*64] = 16 MB

  hipLaunchKernelGGL(kv_partial_kernel, dim3(BH * NCHUNK), dim3(256), 0, stream,
                     k, v, partial);
  hipLaunchKernelGGL(kv_reduce_kernel, dim3(256), dim3(256), 0, stream,
                     partial, kvf);
  hipLaunchKernelGGL(out_kernel, dim3(BH * 64), dim3(256), 0, stream,
                     q, kvf, out);
}